// Round 6
// baseline (426.963 us; speedup 1.0000x reference)
//
#include <hip/hip_runtime.h>
#include <stdint.h>

// ---------------------------------------------------------------------------
// RowParallelLinearSparse: out[M,N] = x[M,K] · (W ⊙ nm_mask(W))[N,K]^T + bias
// M=16384 (S*B), N=O=2048, K=H=2048.  bf16 MFMA.
//
// GEMM v6: LDS-bandwidth fix.  R2/R3/R5 all capped at MfmaUtil 37% because
// A+B in LDS needs 103 B/cyc/CU (reads 192K + stage-writes 64K per 2483-cyc
// K-tile) vs ~85 achievable.  v6: B-fragments load DIRECTLY global(L2)->VGPR
// (per-lane dwordx4; B panel is 1 MB/XCD, L2-resident via XCD-ownership map),
// double-buffered one K-tile ahead.  A stays in LDS: ring-3 bufs (96 KiB),
// global_load_lds w=16, XOR swizzle (verified conflict-free).  LDS demand
// drops to 64 B/cyc.  One barrier per K-tile (only A needs block rendezvous).
//
// vmcnt ledger (per tile t issue order: B(t+1) 8 reg-loads, A(t+2) 4 asyncs;
// in-order retirement):  end-of-t outstanding = [A(t+1)4, B(t+1)8, A(t+2)4];
// vmcnt(4) leaves A(t+2), drains A(t+1)+B(t+1) = exactly what tile t+1 needs.
// Tail t+1==NT-1: outstanding 12, vmcnt(0).  Prologue: B(0),A(0),A(1) then
// vmcnt(4) = same invariant.  Requires NT even, NT>=2 (K=2048 -> NT=32).
// WAR on ring-3: STG(t+2) (issued tile t, after barrier) vs reads of A(t-1)
// from same buf: those reads lgkm-drain before their MFMAs, which precede
// the end-of-(t-1) barrier all waves crossed.  Safe with 1 barrier/tile.
// ---------------------------------------------------------------------------

typedef short  bf16x8  __attribute__((ext_vector_type(8)));
typedef float  floatx4 __attribute__((ext_vector_type(4)));

#define AS1 __attribute__((address_space(1)))
#define AS3 __attribute__((address_space(3)))

__device__ __forceinline__ void async_copy16(const void* g, void* l) {
    __builtin_amdgcn_global_load_lds((const AS1 unsigned int*)g,
                                     (AS3 unsigned int*)l, 16, 0, 0);
}

__device__ __forceinline__ unsigned short f2bf(float f) {
    union { float f; unsigned int u; } v;
    v.f = f;
    unsigned int r = (v.u + 0x7fffu + ((v.u >> 16) & 1u)) >> 16;  // RNE
    return (unsigned short)r;
}

// --- fused prep: blocks [0,2048) convert x fp32->bf16 (contiguous lanes,
//     grid-stride); blocks [2048,...) sparsify W (2:4, stable-argsort ties).
#define CVT_BLOCKS 2048
__global__ __launch_bounds__(256) void cvt_sparsify(
    const float4* __restrict__ x, uint2* __restrict__ xb, long n4,
    const float4* __restrict__ W, unsigned long long* __restrict__ Wb,
    int ngroups) {
    if (blockIdx.x < CVT_BLOCKS) {
        const int lane = threadIdx.x & 63;
        const long wave   = ((long)blockIdx.x * 256 + threadIdx.x) >> 6;
        const long nwaves = (long)CVT_BLOCKS * 256 / 64;
        for (long base = wave * 128; base < n4; base += nwaves * 128) {
            const long i0 = base + lane;
            const long i1 = base + 64 + lane;
            float4 f0 = x[i0];
            float4 f1 = x[i1];
            uint2 o0, o1;
            o0.x = (unsigned)f2bf(f0.x) | ((unsigned)f2bf(f0.y) << 16);
            o0.y = (unsigned)f2bf(f0.z) | ((unsigned)f2bf(f0.w) << 16);
            o1.x = (unsigned)f2bf(f1.x) | ((unsigned)f2bf(f1.y) << 16);
            o1.y = (unsigned)f2bf(f1.z) | ((unsigned)f2bf(f1.w) << 16);
            xb[i0] = o0;
            xb[i1] = o1;
        }
    } else {
        const int g = (blockIdx.x - CVT_BLOCKS) * 256 + threadIdx.x;
        if (g >= ngroups) return;
        float4 w4 = W[g];
        float v[4] = {w4.x, w4.y, w4.z, w4.w};
        float a[4] = {fabsf(w4.x), fabsf(w4.y), fabsf(w4.z), fabsf(w4.w)};
        unsigned long long packed = 0;
#pragma unroll
        for (int i = 0; i < 4; i++) {
            int rank = 0;
#pragma unroll
            for (int j = 0; j < 4; j++)
                rank += (a[j] < a[i]) || (a[j] == a[i] && j < i);
            unsigned short b = (rank >= 2) ? f2bf(v[i]) : (unsigned short)0;
            packed |= ((unsigned long long)b) << (16 * i);
        }
        Wb[g] = packed;
    }
}

// --- bf16 B^T GEMM: 256x256, BK=64, A in ring-3 LDS, B direct L2->VGPR. -----
__global__ __launch_bounds__(512, 2) void gemm_bt_bf16_v6(
    const unsigned short* __restrict__ A,   // [M,K] bf16
    const unsigned short* __restrict__ B,   // [N,K] bf16 (sparse W)
    const float* __restrict__ bias,         // [N]
    float* __restrict__ C,                  // [M,N] fp32
    int M, int N, int K) {
    __shared__ unsigned short lA[3][256 * 64];   // ring-3, 96 KiB total

    const int tid  = threadIdx.x;
    const int w    = tid >> 6;       // wave 0..7
    const int lane = tid & 63;
    const int wr   = w >> 2;         // 0..1 : M-half within tile
    const int wc   = w & 3;          // 0..3 : N-quarter (64 cols)

    const int id  = blockIdx.x;
    const int nbx = N >> 8;
    int bm, bn;
    if (nbx == 8) {                  // XCD-ownership (HW round-robins id&7)
        bn = (id & 7) << 8;
        bm = (id >> 3) << 8;
    } else {
        bn = (id % nbx) << 8;
        bm = (id / nbx) << 8;
    }

    // ---- A staging (global_load_lds 16B/lane; wave stages 32 rows) ---------
    // Swizzle LDS[r][c8] = global[r][c8 ^ (r&7)]; 8-row-aligned slabs ->
    // source chunk collapses to (L&7) ^ (L>>3).
    const int sr8 = lane >> 3;                       // 0..7
    const int scw = ((lane & 7) ^ sr8) * 8;          // pre-swizzled source col
    const unsigned short* Agp = A + (size_t)(bm + w * 32 + sr8) * K + scw;

    // ---- A fragment reads (ds_read_b128), swizzled chunk -------------------
    const int fm   = lane & 15;
    const int q    = lane >> 4;
    const int c0   = (q ^ (fm & 7)) * 8;             // ks=0; ks=1 -> c0 ^ 32
    const int arow = (wr * 64 + fm) * 64;            // within 256x64 buffer

    // ---- B direct-load base: lane (fm,q) reads row bn+wc*64+jj*16+fm,
    //      k = kt + ks*32 + q*8  (16B contiguous per lane) -------------------
    const unsigned short* Bw = B + (size_t)(bn + wc * 64 + fm) * K + q * 8;

    floatx4 acc[8][4];
#pragma unroll
    for (int i = 0; i < 8; i++)
#pragma unroll
        for (int j = 0; j < 4; j++)
            acc[i][j] = (floatx4){0.f, 0.f, 0.f, 0.f};

    bf16x8 bR0[4][2], bR1[4][2];      // B frag double-buffer (const-indexed)

    const int NT = K >> 6;            // 32 K-tiles; requires NT even, >= 2

#define LOADB(T, DST)                                                     \
    {                                                                     \
        const unsigned short* bp = Bw + ((size_t)(T) << 6);               \
        _Pragma("unroll")                                                 \
        for (int jj = 0; jj < 4; jj++)                                    \
            _Pragma("unroll")                                             \
            for (int ks = 0; ks < 2; ks++)                                \
                DST[jj][ks] = *(const bf16x8*)(bp + (size_t)jj * 16 * K + \
                                               ks * 32);                  \
    }
#define STG(T)                                                            \
    {                                                                     \
        const size_t k0 = (size_t)(T) << 6;                               \
        unsigned short* ld = &lA[(T) % 3][w * 2048];                      \
        _Pragma("unroll")                                                 \
        for (int i2 = 0; i2 < 4; i2++)                                    \
            async_copy16(Agp + (size_t)i2 * 8 * K + k0, ld + i2 * 512);   \
    }
#define BAR()                                                             \
    {                                                                     \
        asm volatile("" ::: "memory");                                    \
        __builtin_amdgcn_s_barrier();                                     \
        asm volatile("" ::: "memory");                                    \
    }
// One K-tile: 16 ds_read_b128 (A), 64 MFMA in 4 clusters of 16, issue next-B
// and next-next-A at top; single trailing vmcnt+barrier rendezvous.
#define TILE(T, BC, BN)                                                   \
    {                                                                     \
        if ((T) + 1 < NT) LOADB((T) + 1, BN);                             \
        if ((T) + 2 < NT) STG((T) + 2);                                   \
        const unsigned short* lb = &lA[(T) % 3][0];                       \
        _Pragma("unroll")                                                 \
        for (int mh = 0; mh < 2; mh++)                                    \
            _Pragma("unroll")                                             \
            for (int pr = 0; pr < 2; pr++) {                              \
                const int rb = arow + mh * 8192 + pr * 2048;              \
                bf16x8 a00 = *(const bf16x8*)&lb[rb + c0];                \
                bf16x8 a01 = *(const bf16x8*)&lb[rb + (c0 ^ 32)];         \
                bf16x8 a10 = *(const bf16x8*)&lb[rb + 1024 + c0];         \
                bf16x8 a11 = *(const bf16x8*)&lb[rb + 1024 + (c0 ^ 32)];  \
                const int i0 = mh * 4 + pr * 2;                           \
                __builtin_amdgcn_s_setprio(1);                            \
                _Pragma("unroll")                                         \
                for (int jj = 0; jj < 4; jj++) {                          \
                    acc[i0][jj] = __builtin_amdgcn_mfma_f32_16x16x32_bf16(\
                        a00, BC[jj][0], acc[i0][jj], 0, 0, 0);            \
                    acc[i0][jj] = __builtin_amdgcn_mfma_f32_16x16x32_bf16(\
                        a01, BC[jj][1], acc[i0][jj], 0, 0, 0);            \
                    acc[i0 + 1][jj] =                                     \
                        __builtin_amdgcn_mfma_f32_16x16x32_bf16(          \
                            a10, BC[jj][0], acc[i0 + 1][jj], 0, 0, 0);    \
                    acc[i0 + 1][jj] =                                     \
                        __builtin_amdgcn_mfma_f32_16x16x32_bf16(          \
                            a11, BC[jj][1], acc[i0 + 1][jj], 0, 0, 0);    \
                }                                                         \
                __builtin_amdgcn_s_setprio(0);                            \
            }                                                             \
        if ((T) + 1 < NT) {                                               \
            if ((T) + 1 == NT - 1) {                                      \
                asm volatile("s_waitcnt vmcnt(0)" ::: "memory");          \
            } else {                                                      \
                asm volatile("s_waitcnt vmcnt(4)" ::: "memory");          \
            }                                                             \
            BAR();                                                        \
        }                                                                 \
    }

    // prologue: B(0)->bR0, stage A(0),A(1); drain B0+A0, keep A1 in flight.
    LOADB(0, bR0);
    STG(0);
    STG(1);
    asm volatile("s_waitcnt vmcnt(4)" ::: "memory");
    BAR();

    for (int t = 0; t < NT; t += 2) {
        TILE(t, bR0, bR1);
        TILE(t + 1, bR1, bR0);
    }

#undef LOADB
#undef STG
#undef BAR
#undef TILE

    // epilogue: C/D layout col=lane&15, row=(lane>>4)*4+reg (m89-verified)
    // row = bm + (i>>2)*128 + wr*64 + (i&3)*16 + cm4 + r; col = bn+wc*64+j*16+cn
    const int cn  = lane & 15;
    const int cm4 = (lane >> 4) * 4;
#pragma unroll
    for (int j = 0; j < 4; j++) {
        const int col = bn + wc * 64 + j * 16 + cn;
        const float bv = bias[col];
#pragma unroll
        for (int i = 0; i < 8; i++) {
            const size_t rbase =
                (size_t)(bm + (i >> 2) * 128 + wr * 64 + (i & 3) * 16 + cm4) * N
                + col;
#pragma unroll
            for (int r = 0; r < 4; r++)
                C[rbase + (size_t)r * N] = acc[i][j][r] + bv;
        }
    }
}

extern "C" void kernel_launch(void* const* d_in, const int* in_sizes, int n_in,
                              void* d_out, int out_size, void* d_ws, size_t ws_size,
                              hipStream_t stream) {
    const float* x    = (const float*)d_in[0];   // [S,B,H] fp32
    const float* w    = (const float*)d_in[1];   // [O,H]  fp32
    const float* bias = (const float*)d_in[2];   // [O]    fp32
    float* out = (float*)d_out;

    const int O = in_sizes[2];
    const int H = in_sizes[1] / O;
    const long M = (long)in_sizes[0] / H;        // S*B = 16384

    unsigned short* xb = (unsigned short*)d_ws;            // [M*H] bf16
    unsigned short* wb = xb + (size_t)M * H;               // [O*H] bf16

    const long n4 = (long)M * H / 4;
    const int ng = O * H / 4;
    const int prep_blocks = CVT_BLOCKS + (ng + 255) / 256;
    cvt_sparsify<<<dim3(prep_blocks), dim3(256), 0, stream>>>(
        (const float4*)x, (uint2*)xb, n4,
        (const float4*)w, (unsigned long long*)wb, ng);

    const int nblocks = (int)((M / 256) * ((long)O / 256));   // 512, 1D grid
    gemm_bt_bf16_v6<<<dim3(nblocks), dim3(512), 0, stream>>>(
        xb, wb, bias, out, (int)M, O, H);
}

// Round 7
// 355.885 us; speedup vs baseline: 1.1997x; 1.1997x over previous
//
#include <hip/hip_runtime.h>
#include <stdint.h>

// ---------------------------------------------------------------------------
// RowParallelLinearSparse: out[M,N] = x[M,K] · (W ⊙ nm_mask(W))[N,K]^T + bias
// M=16384 (S*B), N=O=2048, K=H=2048.  bf16 MFMA.
//
// GEMM v7 = R5 (best, 153 µs) + cache-hygiene: C stored non-temporally
// (C is write-once — stop it evicting A/B panels from L2/L3); prep reads
// x,W non-temporally (read-once streams — keep L3 free so xb/wb stay
// resident for the GEMM).  GEMM schedule byte-identical to R5:
// 256x256 tile, BK=64, 8 waves, dbuf LDS halves (128 KiB), 4-phase
// C-quadrant walk (reads/phase 12,4,8,0), straddled wave-output mapping,
// counted vmcnt(4) (never 0 in steady state), XOR-swizzled LDS (verified
// SQ_LDS_BANK_CONFLICT=0), XCD-ownership N-columns.
//
// vmcnt ledger (2 loads/half; stage during tile t for t+1: A0@ph1, B0@ph2,
// B1@ph3, A1@ph4; in-order retirement; checkpoints keep 2 newest halves):
//   end-ph4(t-1) vmcnt(4): drains A0(t),B0(t)  -> ph1 reads A0,B0   OK
//   end-ph1(t)   vmcnt(4): drains B1(t)        -> ph2 reads B1      OK
//   end-ph2(t)   vmcnt(4): drains A1(t)        -> ph3 reads A1      OK
//   ph4: no reads.  Tail t=NT-1: vmcnt(2)/(0) at ph1/ph2.  NT >= 2.
// ---------------------------------------------------------------------------

typedef short  bf16x8  __attribute__((ext_vector_type(8)));
typedef float  floatx4 __attribute__((ext_vector_type(4)));
typedef float  f32x4   __attribute__((ext_vector_type(4)));

#define AS1 __attribute__((address_space(1)))
#define AS3 __attribute__((address_space(3)))

__device__ __forceinline__ void async_copy16(const void* g, void* l) {
    __builtin_amdgcn_global_load_lds((const AS1 unsigned int*)g,
                                     (AS3 unsigned int*)l, 16, 0, 0);
}

__device__ __forceinline__ unsigned short f2bf(float f) {
    union { float f; unsigned int u; } v;
    v.f = f;
    unsigned int r = (v.u + 0x7fffu + ((v.u >> 16) & 1u)) >> 16;  // RNE
    return (unsigned short)r;
}

// --- fused prep: blocks [0,2048) convert x fp32->bf16 (contiguous lanes,
//     grid-stride, NT loads); blocks [2048,...) sparsify W (2:4,
//     stable-argsort ties, NT loads).
#define CVT_BLOCKS 2048
__global__ __launch_bounds__(256) void cvt_sparsify(
    const float* __restrict__ x, uint2* __restrict__ xb, long n4,
    const float* __restrict__ W, unsigned long long* __restrict__ Wb,
    int ngroups) {
    if (blockIdx.x < CVT_BLOCKS) {
        const f32x4* xv = (const f32x4*)x;
        const int lane = threadIdx.x & 63;
        const long wave   = ((long)blockIdx.x * 256 + threadIdx.x) >> 6;
        const long nwaves = (long)CVT_BLOCKS * 256 / 64;
        for (long base = wave * 128; base < n4; base += nwaves * 128) {
            const long i0 = base + lane;
            const long i1 = base + 64 + lane;
            f32x4 f0 = __builtin_nontemporal_load(&xv[i0]);
            f32x4 f1 = __builtin_nontemporal_load(&xv[i1]);
            uint2 o0, o1;
            o0.x = (unsigned)f2bf(f0.x) | ((unsigned)f2bf(f0.y) << 16);
            o0.y = (unsigned)f2bf(f0.z) | ((unsigned)f2bf(f0.w) << 16);
            o1.x = (unsigned)f2bf(f1.x) | ((unsigned)f2bf(f1.y) << 16);
            o1.y = (unsigned)f2bf(f1.z) | ((unsigned)f2bf(f1.w) << 16);
            xb[i0] = o0;                 // cached: GEMM re-reads xb
            xb[i1] = o1;
        }
    } else {
        const int g = (blockIdx.x - CVT_BLOCKS) * 256 + threadIdx.x;
        if (g >= ngroups) return;
        const f32x4* Wv = (const f32x4*)W;
        f32x4 w4 = __builtin_nontemporal_load(&Wv[g]);
        float v[4] = {w4.x, w4.y, w4.z, w4.w};
        float a[4] = {fabsf(w4.x), fabsf(w4.y), fabsf(w4.z), fabsf(w4.w)};
        unsigned long long packed = 0;
#pragma unroll
        for (int i = 0; i < 4; i++) {
            int rank = 0;
#pragma unroll
            for (int j = 0; j < 4; j++)
                rank += (a[j] < a[i]) || (a[j] == a[i] && j < i);
            unsigned short b = (rank >= 2) ? f2bf(v[i]) : (unsigned short)0;
            packed |= ((unsigned long long)b) << (16 * i);
        }
        Wb[g] = packed;                  // cached: GEMM re-reads wb
    }
}

// --- bf16 B^T GEMM: 256x256, BK=64, dbuf halves, straddled quadrant walk. ---
__global__ __launch_bounds__(512, 2) void gemm_bt_bf16_v7(
    const unsigned short* __restrict__ A,   // [M,K] bf16
    const unsigned short* __restrict__ B,   // [N,K] bf16 (sparse W)
    const float* __restrict__ bias,         // [N]
    float* __restrict__ C,                  // [M,N] fp32
    int M, int N, int K) {
    __shared__ unsigned short lA[2][2][128 * 64];   // [dbuf][Mhalf] 64 KiB
    __shared__ unsigned short lB[2][2][128 * 64];   // [dbuf][Nhalf] 64 KiB

    const int tid  = threadIdx.x;
    const int w    = tid >> 6;       // wave 0..7
    const int lane = tid & 63;
    const int wr   = w >> 2;         // 0..1
    const int wc   = w & 3;          // 0..3

    const int id  = blockIdx.x;
    const int nbx = N >> 8;
    int bm, bn;
    if (nbx == 8) {                  // XCD-ownership (HW round-robins id&7)
        bn = (id & 7) << 8;
        bm = (id >> 3) << 8;
    } else {
        bn = (id % nbx) << 8;
        bm = (id / nbx) << 8;
    }

    // ---- staging (global_load_lds 16B/lane, linear LDS dest) ---------------
    const int sr8 = lane >> 3;                       // 0..7
    const int scw = ((lane & 7) ^ sr8) * 8;          // pre-swizzled source col
    const unsigned short* Agp = A + (size_t)(bm + w * 8 + sr8) * K + scw;
    const unsigned short* Bgp = B + (size_t)(bn + w * 8 + sr8) * K + scw;
    const int sl = w * 512;          // wave's 8-row slab within a half (elems)

    // ---- fragment reads (ds_read_b128) -------------------------------------
    const int fm   = lane & 15;
    const int q    = lane >> 4;
    const int x0   = (q ^ (fm & 7)) * 8;             // ks=0; ks=1 -> x0 ^ 32
    const int arow = (wr * 64 + fm) * 64;            // + ii*1024, in half-array
    const int brow = (wc * 32 + fm) * 64;            // + jj*1024

    floatx4 acc[8][4];
#pragma unroll
    for (int i = 0; i < 8; i++)
#pragma unroll
        for (int j = 0; j < 4; j++)
            acc[i][j] = (floatx4){0.f, 0.f, 0.f, 0.f};

    const int NT = K >> 6;            // 32 K-tiles (requires NT >= 2)

#define STG_A(t, bf, mh)                                                  \
    {                                                                     \
        const size_t k0 = (size_t)(t) << 6;                               \
        async_copy16(Agp + (size_t)((mh) * 128) * K + k0,                 \
                     &lA[bf][mh][sl]);                                    \
        async_copy16(Agp + (size_t)((mh) * 128 + 64) * K + k0,            \
                     &lA[bf][mh][sl + 4096]);                             \
    }
#define STG_B(t, bf, nh)                                                  \
    {                                                                     \
        const size_t k0 = (size_t)(t) << 6;                               \
        async_copy16(Bgp + (size_t)((nh) * 128) * K + k0,                 \
                     &lB[bf][nh][sl]);                                    \
        async_copy16(Bgp + (size_t)((nh) * 128 + 64) * K + k0,            \
                     &lB[bf][nh][sl + 4096]);                             \
    }
#define BAR()                                                             \
    {                                                                     \
        asm volatile("" ::: "memory");                                    \
        __builtin_amdgcn_s_barrier();                                     \
        asm volatile("" ::: "memory");                                    \
    }

    // prologue: stage tile 0 in ledger order A0,B0,B1,A1
    STG_A(0, 0, 0);
    STG_B(0, 0, 0);
    STG_B(0, 0, 1);
    STG_A(0, 0, 1);
    asm volatile("s_waitcnt vmcnt(4)" ::: "memory");  // A0,B0 landed
    BAR();

    bf16x8 aF[4][2], bF[4][2];

    for (int t = 0; t < NT; ++t) {
        const int  b  = t & 1;
        const bool st = (t + 1) < NT;

        // ---- ph1 (mh0,nh0): read A0 (8) + B j0..1 (4) ∥ stage A0(t+1) ------
#pragma unroll
        for (int ii = 0; ii < 4; ii++) {
            aF[ii][0] = *(const bf16x8*)&lA[b][0][arow + ii * 1024 + x0];
            aF[ii][1] = *(const bf16x8*)&lA[b][0][arow + ii * 1024 + (x0 ^ 32)];
        }
#pragma unroll
        for (int jj = 0; jj < 2; jj++) {
            bF[jj][0] = *(const bf16x8*)&lB[b][0][brow + jj * 1024 + x0];
            bF[jj][1] = *(const bf16x8*)&lB[b][0][brow + jj * 1024 + (x0 ^ 32)];
        }
        if (st) STG_A(t + 1, b ^ 1, 0);
        asm volatile("s_waitcnt lgkmcnt(8)" ::: "memory");
        BAR();
        asm volatile("s_waitcnt lgkmcnt(0)" ::: "memory");
        __builtin_amdgcn_s_setprio(1);
#pragma unroll
        for (int ks = 0; ks < 2; ks++)
#pragma unroll
            for (int ii = 0; ii < 4; ii++)
#pragma unroll
                for (int jj = 0; jj < 2; jj++)
                    acc[ii][jj] = __builtin_amdgcn_mfma_f32_16x16x32_bf16(
                        aF[ii][ks], bF[jj][ks], acc[ii][jj], 0, 0, 0);
        __builtin_amdgcn_s_setprio(0);
        if (st) { asm volatile("s_waitcnt vmcnt(4)" ::: "memory"); }
        else    { asm volatile("s_waitcnt vmcnt(2)" ::: "memory"); }
        BAR();

        // ---- ph2 (mh0,nh1): read B j2..3 (4) ∥ stage B0(t+1) ---------------
#pragma unroll
        for (int jj = 0; jj < 2; jj++) {
            bF[2 + jj][0] = *(const bf16x8*)&lB[b][1][brow + jj * 1024 + x0];
            bF[2 + jj][1] = *(const bf16x8*)&lB[b][1][brow + jj * 1024 + (x0 ^ 32)];
        }
        if (st) STG_B(t + 1, b ^ 1, 0);
        BAR();
        asm volatile("s_waitcnt lgkmcnt(0)" ::: "memory");
        __builtin_amdgcn_s_setprio(1);
#pragma unroll
        for (int ks = 0; ks < 2; ks++)
#pragma unroll
            for (int ii = 0; ii < 4; ii++)
#pragma unroll
                for (int jj = 0; jj < 2; jj++)
                    acc[ii][2 + jj] = __builtin_amdgcn_mfma_f32_16x16x32_bf16(
                        aF[ii][ks], bF[2 + jj][ks], acc[ii][2 + jj], 0, 0, 0);
        __builtin_amdgcn_s_setprio(0);
        if (st) { asm volatile("s_waitcnt vmcnt(4)" ::: "memory"); }
        else    { asm volatile("s_waitcnt vmcnt(0)" ::: "memory"); }
        BAR();

        // ---- ph3 (mh1,nh1): read A1 (8, reuse regs) ∥ stage B1(t+1) --------
#pragma unroll
        for (int ii = 0; ii < 4; ii++) {
            aF[ii][0] = *(const bf16x8*)&lA[b][1][arow + ii * 1024 + x0];
            aF[ii][1] = *(const bf16x8*)&lA[b][1][arow + ii * 1024 + (x0 ^ 32)];
        }
        if (st) STG_B(t + 1, b ^ 1, 1);
        BAR();
        asm volatile("s_waitcnt lgkmcnt(0)" ::: "memory");
        __builtin_amdgcn_s_setprio(1);
#pragma unroll
        for (int ks = 0; ks < 2; ks++)
#pragma unroll
            for (int ii = 0; ii < 4; ii++)
#pragma unroll
                for (int jj = 0; jj < 2; jj++)
                    acc[4 + ii][2 + jj] = __builtin_amdgcn_mfma_f32_16x16x32_bf16(
                        aF[ii][ks], bF[2 + jj][ks], acc[4 + ii][2 + jj], 0, 0, 0);
        __builtin_amdgcn_s_setprio(0);
        BAR();

        // ---- ph4 (mh1,nh0): no reads ∥ stage A1(t+1) -----------------------
        if (st) STG_A(t + 1, b ^ 1, 1);
        __builtin_amdgcn_s_setprio(1);
#pragma unroll
        for (int ks = 0; ks < 2; ks++)
#pragma unroll
            for (int ii = 0; ii < 4; ii++)
#pragma unroll
                for (int jj = 0; jj < 2; jj++)
                    acc[4 + ii][jj] = __builtin_amdgcn_mfma_f32_16x16x32_bf16(
                        aF[ii][ks], bF[jj][ks], acc[4 + ii][jj], 0, 0, 0);
        __builtin_amdgcn_s_setprio(0);
        if (st) { asm volatile("s_waitcnt vmcnt(4)" ::: "memory"); }
        BAR();
    }

#undef STG_A
#undef STG_B
#undef BAR

    // epilogue: C/D layout col=lane&15, row=(lane>>4)*4+reg (m89-verified).
    // NON-TEMPORAL stores: C is write-once; keep it out of L2/L3 so A/B
    // panels stay resident (the R5 FETCH=270MB over-fetch suspect).
    const int cn  = lane & 15;
    const int cm4 = (lane >> 4) * 4;
#pragma unroll
    for (int j = 0; j < 4; j++) {
        const int col = bn + (j >> 1) * 128 + wc * 32 + (j & 1) * 16 + cn;
        const float bv = bias[col];
#pragma unroll
        for (int i = 0; i < 8; i++) {
            const size_t rbase =
                (size_t)(bm + (i >> 2) * 128 + wr * 64 + (i & 3) * 16 + cm4) * N
                + col;
#pragma unroll
            for (int r = 0; r < 4; r++)
                __builtin_nontemporal_store(acc[i][j][r] + bv,
                                            &C[rbase + (size_t)r * N]);
        }
    }
}

extern "C" void kernel_launch(void* const* d_in, const int* in_sizes, int n_in,
                              void* d_out, int out_size, void* d_ws, size_t ws_size,
                              hipStream_t stream) {
    const float* x    = (const float*)d_in[0];   // [S,B,H] fp32
    const float* w    = (const float*)d_in[1];   // [O,H]  fp32
    const float* bias = (const float*)d_in[2];   // [O]    fp32
    float* out = (float*)d_out;

    const int O = in_sizes[2];
    const int H = in_sizes[1] / O;
    const long M = (long)in_sizes[0] / H;        // S*B = 16384

    unsigned short* xb = (unsigned short*)d_ws;            // [M*H] bf16
    unsigned short* wb = xb + (size_t)M * H;               // [O*H] bf16

    const long n4 = (long)M * H / 4;
    const int ng = O * H / 4;
    const int prep_blocks = CVT_BLOCKS + (ng + 255) / 256;
    cvt_sparsify<<<dim3(prep_blocks), dim3(256), 0, stream>>>(
        x, (uint2*)xb, n4, w, (unsigned long long*)wb, ng);

    const int nblocks = (int)((M / 256) * ((long)O / 256));   // 512, 1D grid
    gemm_bt_bf16_v7<<<dim3(nblocks), dim3(512), 0, stream>>>(
        xb, wb, bias, out, (int)M, O, H);
}